// Round 6
// baseline (83.976 us; speedup 1.0000x reference)
//
#include <hip/hip_runtime.h>

// Sliding-window min (STL Always_[16,64]):
//   out[t][b] = min_{j=15..63} xpad[t-j][b],   xpad[s<0] = 1e6
// R6 = R5 with clang native vector type (float4 class isn't accepted by
// __builtin_nontemporal_store). 16 B/lane loads+stores — the 6.3 TB/s copy
// ubench shape. C_TILE=32 bounds the streaming live set (~180 VGPR).

#define T_DIM 8192
#define B_DIM 4096
#define C_TILE 32               // outputs per thread along T
#define ALEN (C_TILE + 48)      // inputs per thread (window width 49)
#define LARGE_VAL 1e6f

typedef float f32x4 __attribute__((ext_vector_type(4)));

__device__ __forceinline__ f32x4 fmin4(f32x4 a, f32x4 b) {
    f32x4 r;
    r.x = fminf(a.x, b.x); r.y = fminf(a.y, b.y);
    r.z = fminf(a.z, b.z); r.w = fminf(a.w, b.w);
    return r;
}

__global__ __launch_bounds__(256)
void Temporal_Operator_kernel(const float* __restrict__ x,
                              float* __restrict__ out) {
    const int c4 = blockIdx.x * blockDim.x + threadIdx.x;   // float4 column
    const int t0 = blockIdx.y * C_TILE;                     // output tile start
    const long base = (long)t0 - 63;                        // first input row
    const int ROW4 = B_DIM / 4;                             // row stride in f32x4

    const f32x4* __restrict__ xp = (const f32x4*)x;
    f32x4* __restrict__ op = (f32x4*)out;

    // Load inputs (negative rows -> LARGE; wave-uniform predicate, y-tiles 0,1).
    f32x4 arr[ALEN];
    #pragma unroll
    for (int i = 0; i < ALEN; ++i) {
        long s = base + i;
        if (s >= 0) {
            arr[i] = xp[s * ROW4 + c4];
        } else {
            arr[i] = (f32x4){LARGE_VAL, LARGE_VAL, LARGE_VAL, LARGE_VAL};
        }
    }

    // Log-doubling forward window mins, in place.
    #pragma unroll
    for (int i = 0; i < ALEN - 1; ++i)  arr[i] = fmin4(arr[i], arr[i + 1]);   // w2
    #pragma unroll
    for (int i = 0; i < ALEN - 3; ++i)  arr[i] = fmin4(arr[i], arr[i + 2]);   // w4
    #pragma unroll
    for (int i = 0; i < ALEN - 7; ++i)  arr[i] = fmin4(arr[i], arr[i + 4]);   // w8
    #pragma unroll
    for (int i = 0; i < ALEN - 15; ++i) arr[i] = fmin4(arr[i], arr[i + 8]);   // w16
    #pragma unroll
    for (int i = 0; i < ALEN - 31; ++i) arr[i] = fmin4(arr[i], arr[i + 16]);  // w32

    // w49[c] = min(w32[c], w32[c+17]) covers [c, c+48]; stream past caches.
    #pragma unroll
    for (int c = 0; c < C_TILE; ++c) {
        __builtin_nontemporal_store(fmin4(arr[c], arr[c + 17]),
                                    &op[(long)(t0 + c) * ROW4 + c4]);
    }
}

extern "C" void kernel_launch(void* const* d_in, const int* in_sizes, int n_in,
                              void* d_out, int out_size, void* d_ws, size_t ws_size,
                              hipStream_t stream) {
    const float* x = (const float*)d_in[0];
    float* out = (float*)d_out;

    dim3 block(256, 1, 1);
    dim3 grid((B_DIM / 4) / 256, T_DIM / C_TILE, 1);   // 4 x 256 blocks
    Temporal_Operator_kernel<<<grid, block, 0, stream>>>(x, out);
}

// Round 7
// 56.182 us; speedup vs baseline: 1.4947x; 1.4947x over previous
//
#include <hip/hip_runtime.h>

// Sliding-window min (STL Always_[16,64]):
//   out[t][b] = min_{j=15..63} xpad[t-j][b],   xpad[s<0] = 1e6
// R7: occupancy x halo-amp middle point. Evidence so far (all single-variable):
//   width:  scalar = float2 (null), float4 NEGATIVE (VGPR 220 -> occ 10%, 84us)
//   amp:    2.5x -> 1.375x = -5% (R3)
//   nt:     null (L3 is memory-side; writes transit it regardless)
//   best:   scalar C_TILE=128, 56us, fabric demand ~5.7 TB/s vs 6.3 ceiling
// C_TILE=64: amp 1.75, VGPR ~75 -> ~2x R3's waves/CU for latency hiding.

#define T_DIM 8192
#define B_DIM 4096
#define C_TILE 64               // outputs per thread along T
#define ALEN (C_TILE + 48)      // inputs per thread (window width 49)
#define LARGE_VAL 1e6f

__global__ __launch_bounds__(256)
void Temporal_Operator_kernel(const float* __restrict__ x,
                              float* __restrict__ out) {
    const int b  = blockIdx.x * blockDim.x + threadIdx.x;   // column
    const int t0 = blockIdx.y * C_TILE;                     // output tile start
    const long base = (long)t0 - 63;                        // first input row

    // Load inputs (negative rows -> LARGE; wave-uniform predicate, y-tiles 0).
    float arr[ALEN];
    #pragma unroll
    for (int i = 0; i < ALEN; ++i) {
        long s = base + i;
        arr[i] = (s >= 0) ? x[s * B_DIM + b] : LARGE_VAL;
    }

    // Log-doubling forward window mins, in place:
    // after pass k, arr[i] = min(x[i .. i+k-1]) over the valid range.
    #pragma unroll
    for (int i = 0; i < ALEN - 1; ++i)  arr[i] = fminf(arr[i], arr[i + 1]);   // w2
    #pragma unroll
    for (int i = 0; i < ALEN - 3; ++i)  arr[i] = fminf(arr[i], arr[i + 2]);   // w4
    #pragma unroll
    for (int i = 0; i < ALEN - 7; ++i)  arr[i] = fminf(arr[i], arr[i + 4]);   // w8
    #pragma unroll
    for (int i = 0; i < ALEN - 15; ++i) arr[i] = fminf(arr[i], arr[i + 8]);   // w16
    #pragma unroll
    for (int i = 0; i < ALEN - 31; ++i) arr[i] = fminf(arr[i], arr[i + 16]);  // w32

    // w49[c] = min(w32[c], w32[c+17]) covers [c, c+48]; stream past caches.
    #pragma unroll
    for (int c = 0; c < C_TILE; ++c) {
        __builtin_nontemporal_store(fminf(arr[c], arr[c + 17]),
                                    &out[(long)(t0 + c) * B_DIM + b]);
    }
}

extern "C" void kernel_launch(void* const* d_in, const int* in_sizes, int n_in,
                              void* d_out, int out_size, void* d_ws, size_t ws_size,
                              hipStream_t stream) {
    const float* x = (const float*)d_in[0];
    float* out = (float*)d_out;

    dim3 block(256, 1, 1);
    dim3 grid(B_DIM / 256, T_DIM / C_TILE, 1);   // 16 x 128 blocks
    Temporal_Operator_kernel<<<grid, block, 0, stream>>>(x, out);
}